// Round 1
// baseline (5992.262 us; speedup 1.0000x reference)
//
#include <hip/hip_runtime.h>
#include <math.h>

#define DIM  1024   // hidden dim D
#define NEXP 8      // experts
#define HID  4096   // expert hidden H
#define TOPK 2
#define TN   16     // tokens per MLP block
#define HC   128    // H chunk
#define DC   64     // D chunk

// ---------------- gate: logits -> softmax -> top2 -> routing lists ----------------
__global__ void gate_kernel(const float* __restrict__ x,
                            const float* __restrict__ Wg,
                            const float* __restrict__ bg,
                            int* __restrict__ topk_idx,
                            float* __restrict__ topk_score,
                            int* __restrict__ count,
                            int* __restrict__ lists,
                            int N) {
  int n = blockIdx.x;
  if (n >= N) return;
  int lane = threadIdx.x;
  float acc[NEXP];
#pragma unroll
  for (int e = 0; e < NEXP; ++e) acc[e] = 0.f;
  const float* xr = x + (size_t)n * DIM;
  for (int d = lane; d < DIM; d += 64) {
    float xv = xr[d];
    const float* w = Wg + (size_t)d * NEXP;
#pragma unroll
    for (int e = 0; e < NEXP; ++e) acc[e] += xv * w[e];
  }
#pragma unroll
  for (int off = 32; off > 0; off >>= 1) {
#pragma unroll
    for (int e = 0; e < NEXP; ++e) acc[e] += __shfl_xor(acc[e], off, 64);
  }
  if (lane == 0) {
    float l[NEXP];
#pragma unroll
    for (int e = 0; e < NEXP; ++e) l[e] = acc[e] + bg[e];
    float m = l[0];
#pragma unroll
    for (int e = 1; e < NEXP; ++e) m = fmaxf(m, l[e]);
    float p[NEXP];
    float s = 0.f;
#pragma unroll
    for (int e = 0; e < NEXP; ++e) { p[e] = expf(l[e] - m); s += p[e]; }
    // top-2 by logit (== top-2 by prob), ties -> lowest index (matches lax.top_k)
    int i0 = 0;
#pragma unroll
    for (int e = 1; e < NEXP; ++e) if (l[e] > l[i0]) i0 = e;
    int i1 = (i0 == 0) ? 1 : 0;
#pragma unroll
    for (int e = 0; e < NEXP; ++e) if (e != i0 && l[e] > l[i1]) i1 = e;
    float inv = 1.f / s;
    topk_idx[n * TOPK + 0] = i0;
    topk_idx[n * TOPK + 1] = i1;
    topk_score[n * TOPK + 0] = p[i0] * inv;
    topk_score[n * TOPK + 1] = p[i1] * inv;
    int pos0 = atomicAdd(&count[i0], 1);
    lists[(size_t)i0 * N + pos0] = n * TOPK + 0;
    int pos1 = atomicAdd(&count[i1], 1);
    lists[(size_t)i1 * N + pos1] = n * TOPK + 1;
  }
}

// ---------------- fused 2-layer expert MLP over routed token tiles ----------------
__global__ __launch_bounds__(256) void moe_mlp_kernel(
    const float* __restrict__ x,
    const float* __restrict__ W1,
    const float* __restrict__ b1,
    const float* __restrict__ W2,
    const float* __restrict__ b2,
    const int* __restrict__ count,
    const int* __restrict__ lists,
    const float* __restrict__ topk_score,
    float* __restrict__ pairout,
    float* __restrict__ out,
    int use_pairout, int N) {
  const int e = blockIdx.y;
  const int nc = count[e];
  const int base = blockIdx.x * TN;
  if (base >= nc) return;

  __shared__ float Xs[DC][18];      // [d][token], pad 18 to keep b64 reads aligned + spread banks
  __shared__ float W1s[DC][HC];
  __shared__ float Hs[TN][HC];
  __shared__ int toks[TN];
  __shared__ int kks[TN];
  __shared__ int actv[TN];

  const int tid = threadIdx.x;
  if (tid < TN) {
    int i = base + tid;
    int ent = lists[(size_t)e * N + ((i < nc) ? i : base)];
    toks[tid] = ent >> 1;
    kks[tid]  = ent & 1;
    actv[tid] = (i < nc) ? 1 : 0;
  }
  __syncthreads();

  float Oacc[TN][4];
#pragma unroll
  for (int t = 0; t < TN; ++t) {
    Oacc[t][0] = 0.f; Oacc[t][1] = 0.f; Oacc[t][2] = 0.f; Oacc[t][3] = 0.f;
  }

  const float* W1e = W1 + (size_t)e * DIM * HID;
  const float* W2e = W2 + (size_t)e * HID * DIM;

  const int h4   = (tid & 31) * 4;   // 4 h-columns per thread (phase A)
  const int t0   = (tid >> 5) * 2;   // 2 tokens per thread (phase A)
  const int ldt  = tid >> 4;         // staging: token 0..15
  const int lddq = (tid & 15) * 4;   // staging: d offset

  for (int h0 = 0; h0 < HID; h0 += HC) {
    float ha[2][4];
#pragma unroll
    for (int tt = 0; tt < 2; ++tt) {
      ha[tt][0] = 0.f; ha[tt][1] = 0.f; ha[tt][2] = 0.f; ha[tt][3] = 0.f;
    }

    for (int d0 = 0; d0 < DIM; d0 += DC) {
      // stage X chunk (transposed) and W1 chunk
      float4 xv4 = *(const float4*)(x + (size_t)toks[ldt] * DIM + d0 + lddq);
      Xs[lddq + 0][ldt] = xv4.x;
      Xs[lddq + 1][ldt] = xv4.y;
      Xs[lddq + 2][ldt] = xv4.z;
      Xs[lddq + 3][ldt] = xv4.w;
      {
        const int wrow = tid >> 5;        // 0..7
        const int wcol = (tid & 31) * 4;  // 0..124
#pragma unroll
        for (int p = 0; p < 8; ++p) {
          int dd = wrow + p * 8;
          *(float4*)&W1s[dd][wcol] =
              *(const float4*)(W1e + (size_t)(d0 + dd) * HID + h0 + wcol);
        }
      }
      __syncthreads();
#pragma unroll
      for (int dd = 0; dd < DC; ++dd) {
        float2 xv = *(const float2*)&Xs[dd][t0];
        float4 wv = *(const float4*)&W1s[dd][h4];
        ha[0][0] += xv.x * wv.x; ha[0][1] += xv.x * wv.y;
        ha[0][2] += xv.x * wv.z; ha[0][3] += xv.x * wv.w;
        ha[1][0] += xv.y * wv.x; ha[1][1] += xv.y * wv.y;
        ha[1][2] += xv.y * wv.z; ha[1][3] += xv.y * wv.w;
      }
      __syncthreads();
    }

    // bias + exact gelu, store h tile
    {
      float4 b1v = *(const float4*)(b1 + (size_t)e * HID + h0 + h4);
#pragma unroll
      for (int tt = 0; tt < 2; ++tt) {
        float v0 = ha[tt][0] + b1v.x;
        float v1 = ha[tt][1] + b1v.y;
        float v2 = ha[tt][2] + b1v.z;
        float v3 = ha[tt][3] + b1v.w;
        float4 g;
        g.x = 0.5f * v0 * (1.f + erff(v0 * 0.70710678118654752f));
        g.y = 0.5f * v1 * (1.f + erff(v1 * 0.70710678118654752f));
        g.z = 0.5f * v2 * (1.f + erff(v2 * 0.70710678118654752f));
        g.w = 0.5f * v3 * (1.f + erff(v3 * 0.70710678118654752f));
        *(float4*)&Hs[t0 + tt][h4] = g;
      }
    }
    __syncthreads();

    // phase B: O += H * W2 chunk (W2 rows streamed from global, coalesced)
    const float* w2p = W2e + (size_t)h0 * DIM + tid * 4;
#pragma unroll 2
    for (int h = 0; h < HC; ++h) {
      float4 wv = *(const float4*)w2p;
      w2p += DIM;
#pragma unroll
      for (int t = 0; t < TN; ++t) {
        float hv = Hs[t][h];
        Oacc[t][0] += hv * wv.x; Oacc[t][1] += hv * wv.y;
        Oacc[t][2] += hv * wv.z; Oacc[t][3] += hv * wv.w;
      }
    }
    __syncthreads();
  }

  // epilogue: + b2, write per-(token,k) expert output
  const int c4 = tid * 4;
  float4 b2v = *(const float4*)(b2 + (size_t)e * DIM + c4);
#pragma unroll
  for (int t = 0; t < TN; ++t) {
    if (actv[t]) {
      float o0 = Oacc[t][0] + b2v.x;
      float o1 = Oacc[t][1] + b2v.y;
      float o2 = Oacc[t][2] + b2v.z;
      float o3 = Oacc[t][3] + b2v.w;
      int tok = toks[t], k = kks[t];
      if (use_pairout) {
        float4 o = make_float4(o0, o1, o2, o3);
        *(float4*)(pairout + ((size_t)tok * TOPK + k) * DIM + c4) = o;
      } else {
        float s = topk_score[tok * TOPK + k];
        float* op = out + (size_t)tok * DIM + c4;
        atomicAdd(op + 0, s * o0);
        atomicAdd(op + 1, s * o1);
        atomicAdd(op + 2, s * o2);
        atomicAdd(op + 3, s * o3);
      }
    }
  }
}

// ---------------- combine: out = s0*p0 + s1*p1 ----------------
__global__ void combine_kernel(const float* __restrict__ pairout,
                               const float* __restrict__ topk_score,
                               float* __restrict__ out, int N) {
  int idx = blockIdx.x * blockDim.x + threadIdx.x;
  int total = N * (DIM / 4);
  if (idx >= total) return;
  int n = idx / (DIM / 4);
  int c4 = (idx % (DIM / 4)) * 4;
  float s0 = topk_score[n * TOPK + 0];
  float s1 = topk_score[n * TOPK + 1];
  float4 p0 = *(const float4*)(pairout + ((size_t)n * TOPK + 0) * DIM + c4);
  float4 p1 = *(const float4*)(pairout + ((size_t)n * TOPK + 1) * DIM + c4);
  float4 o;
  o.x = s0 * p0.x + s1 * p1.x;
  o.y = s0 * p0.y + s1 * p1.y;
  o.z = s0 * p0.z + s1 * p1.z;
  o.w = s0 * p0.w + s1 * p1.w;
  *(float4*)(out + (size_t)n * DIM + c4) = o;
}

extern "C" void kernel_launch(void* const* d_in, const int* in_sizes, int n_in,
                              void* d_out, int out_size, void* d_ws, size_t ws_size,
                              hipStream_t stream) {
  const float* x  = (const float*)d_in[0];
  const float* W1 = (const float*)d_in[1];
  const float* b1 = (const float*)d_in[2];
  const float* W2 = (const float*)d_in[3];
  const float* b2 = (const float*)d_in[4];
  const float* Wg = (const float*)d_in[5];
  const float* bg = (const float*)d_in[6];
  float* out = (float*)d_out;
  const int N = in_sizes[0] / DIM;  // 4096 tokens

  char* ws = (char*)d_ws;
  size_t off = 0;
  int* topk_idx = (int*)(ws + off);     off += (size_t)N * TOPK * sizeof(int);
  float* topk_score = (float*)(ws + off); off += (size_t)N * TOPK * sizeof(float);
  int* count = (int*)(ws + off);        off += 256;
  int* lists = (int*)(ws + off);        off += (size_t)NEXP * N * sizeof(int);
  float* pairout = (float*)(ws + off);
  size_t need = off + (size_t)N * TOPK * DIM * sizeof(float);
  int use_pairout = (ws_size >= need) ? 1 : 0;

  hipMemsetAsync(count, 0, 256, stream);
  if (!use_pairout) {
    hipMemsetAsync(out, 0, (size_t)out_size * sizeof(float), stream);
  }

  gate_kernel<<<N, 64, 0, stream>>>(x, Wg, bg, topk_idx, topk_score, count, lists, N);

  dim3 grid((N + TN - 1) / TN, NEXP);
  moe_mlp_kernel<<<grid, 256, 0, stream>>>(x, W1, b1, W2, b2, count, lists,
                                           topk_score, pairout, out, use_pairout, N);

  if (use_pairout) {
    int total = N * (DIM / 4);
    combine_kernel<<<(total + 255) / 256, 256, 0, stream>>>(pairout, topk_score, out, N);
  }
}

// Round 2
// 1382.601 us; speedup vs baseline: 4.3340x; 4.3340x over previous
//
#include <hip/hip_runtime.h>
#include <math.h>

#define DIM  1024   // hidden dim D
#define NEXP 8      // experts
#define HID  4096   // expert hidden H
#define TOPK 2
// fallback-path tile params
#define TN   16
#define HC   128
#define DC   64

typedef __attribute__((ext_vector_type(8))) short bf16x8;
typedef __attribute__((ext_vector_type(4))) float f32x4;

__device__ inline unsigned short f2bf(float f) {
  union { float f; unsigned int u; } v; v.f = f;
  unsigned int u = v.u;
  return (unsigned short)((u + 0x7FFFu + ((u >> 16) & 1u)) >> 16);
}

// ---------------- gate: logits -> softmax -> top2 -> routing lists ----------------
__global__ void gate_kernel(const float* __restrict__ x,
                            const float* __restrict__ Wg,
                            const float* __restrict__ bg,
                            float* __restrict__ topk_score,
                            int* __restrict__ count,
                            int* __restrict__ lists,
                            int N) {
  int n = blockIdx.x;
  if (n >= N) return;
  int lane = threadIdx.x;
  float acc[NEXP];
#pragma unroll
  for (int e = 0; e < NEXP; ++e) acc[e] = 0.f;
  const float* xr = x + (size_t)n * DIM;
  for (int d = lane; d < DIM; d += 64) {
    float xv = xr[d];
    const float* w = Wg + (size_t)d * NEXP;
#pragma unroll
    for (int e = 0; e < NEXP; ++e) acc[e] += xv * w[e];
  }
#pragma unroll
  for (int off = 32; off > 0; off >>= 1) {
#pragma unroll
    for (int e = 0; e < NEXP; ++e) acc[e] += __shfl_xor(acc[e], off, 64);
  }
  if (lane == 0) {
    float l[NEXP];
#pragma unroll
    for (int e = 0; e < NEXP; ++e) l[e] = acc[e] + bg[e];
    float m = l[0];
#pragma unroll
    for (int e = 1; e < NEXP; ++e) m = fmaxf(m, l[e]);
    float p[NEXP];
    float s = 0.f;
#pragma unroll
    for (int e = 0; e < NEXP; ++e) { p[e] = expf(l[e] - m); s += p[e]; }
    int i0 = 0;
#pragma unroll
    for (int e = 1; e < NEXP; ++e) if (l[e] > l[i0]) i0 = e;
    int i1 = (i0 == 0) ? 1 : 0;
#pragma unroll
    for (int e = 0; e < NEXP; ++e) if (e != i0 && l[e] > l[i1]) i1 = e;
    float inv = 1.f / s;
    topk_score[n * TOPK + 0] = p[i0] * inv;
    topk_score[n * TOPK + 1] = p[i1] * inv;
    int pos0 = atomicAdd(&count[i0], 1);
    lists[(size_t)i0 * N + pos0] = n * TOPK + 0;
    int pos1 = atomicAdd(&count[i1], 1);
    lists[(size_t)i1 * N + pos1] = n * TOPK + 1;
  }
}

__global__ void offsets_kernel(const int* __restrict__ count, int* __restrict__ offsets) {
  if (threadIdx.x == 0 && blockIdx.x == 0) {
    int s = 0;
    for (int e = 0; e < NEXP; ++e) { offsets[e] = s; s += count[e]; }
    offsets[NEXP] = s;
  }
}

// gather token rows (sorted by expert) into bf16 Xg; record pair mapping
__global__ void gather_kernel(const float* __restrict__ x,
                              const int* __restrict__ offsets,
                              const int* __restrict__ lists,
                              unsigned short* __restrict__ Xg,
                              int* __restrict__ pairmap,
                              int N) {
  int g = blockIdx.x;
  int e = 0;
  while (e < NEXP - 1 && g >= offsets[e + 1]) ++e;
  int i = g - offsets[e];
  int ent = lists[(size_t)e * N + i];
  int tok = ent >> 1;
  if (threadIdx.x == 0) pairmap[g] = ent;
  float4 v = *((const float4*)(x + (size_t)tok * DIM) + threadIdx.x);
  ushort4 o;
  o.x = f2bf(v.x); o.y = f2bf(v.y); o.z = f2bf(v.z); o.w = f2bf(v.w);
  *((ushort4*)(Xg + (size_t)g * DIM) + threadIdx.x) = o;
}

// ---------------- grouped bf16 MFMA GEMM, 128x128 tile, 4 waves ----------------
// PASS 1: C = gelu(Xg * W1 + b1) -> Hmat (bf16)
// PASS 2: out[tok] += score * (Hmat * W2 + b2)   (atomic, exactly 2 adders/elem)
template <int PASS>
__global__ __launch_bounds__(256) void moe_gemm(
    const unsigned short* __restrict__ Asrc,
    const float* __restrict__ Bsrc,
    const float* __restrict__ bias,
    const int* __restrict__ offsets,
    const int* __restrict__ pairmap,
    const float* __restrict__ score,
    unsigned short* __restrict__ Hmat,
    float* __restrict__ out) {
  constexpr int K  = (PASS == 1) ? DIM : HID;   // reduction dim
  constexpr int NS = (PASS == 1) ? HID : DIM;   // B row stride / C width
  const int e = blockIdx.z;
  const int gbase = offsets[e];
  const int nc = offsets[e + 1] - gbase;
  const int rt = blockIdx.x;
  if (rt * 128 >= nc) return;
  const int rowsvalid = min(128, nc - rt * 128);
  const int ct = blockIdx.y;

  __shared__ unsigned short As[128 * 40];  // [row][k], k-contiguous, stride 40 (80B, 16B-aligned)
  __shared__ unsigned short Bs[128 * 40];  // [col][k], k-contiguous

  const int tid  = threadIdx.x;
  const int lane = tid & 63;
  const int wid  = tid >> 6;
  const int wr = (wid >> 1) * 64;   // wave row base in tile
  const int wc = (wid & 1) * 64;    // wave col base in tile
  const int fr = lane & 15;
  const int fq = lane >> 4;

  f32x4 acc[4][4];
#pragma unroll
  for (int m = 0; m < 4; ++m)
#pragma unroll
    for (int n = 0; n < 4; ++n) acc[m][n] = (f32x4){0.f, 0.f, 0.f, 0.f};

  // A staging: thread -> (row, 16-elem half of 32-k chunk)
  const int ar = tid >> 1;
  const int ak = (tid & 1) * 16;
  int arow = rt * 128 + ((ar < rowsvalid) ? ar : 0);  // clamp pad rows to a valid row
  const unsigned short* Aptr = Asrc + (size_t)(gbase + arow) * K + ak;

  // B staging: thread -> (4 cols, 4 ks); fp32 -> bf16 transpose-pack
  const int bc = (tid & 31) * 4;
  const int bk = (tid >> 5) * 4;
  const float* Bptr = Bsrc + (size_t)e * K * NS + (size_t)bk * NS + ct * 128 + bc;

  for (int k0 = 0; k0 < K; k0 += 32) {
    uint4 av0 = *(const uint4*)(Aptr + k0);
    uint4 av1 = *(const uint4*)(Aptr + k0 + 8);
    const float* bp = Bptr + (size_t)k0 * NS;
    float4 w0 = *(const float4*)(bp);
    float4 w1 = *(const float4*)(bp + NS);
    float4 w2 = *(const float4*)(bp + 2 * NS);
    float4 w3 = *(const float4*)(bp + 3 * NS);

    __syncthreads();  // previous iteration's fragment reads complete

    *(uint4*)&As[ar * 40 + ak]     = av0;
    *(uint4*)&As[ar * 40 + ak + 8] = av1;
    {
      unsigned int p01, p23;
      uint2 pv;
      p01 = (unsigned int)f2bf(w0.x) | ((unsigned int)f2bf(w1.x) << 16);
      p23 = (unsigned int)f2bf(w2.x) | ((unsigned int)f2bf(w3.x) << 16);
      pv.x = p01; pv.y = p23;
      *(uint2*)&Bs[(bc + 0) * 40 + bk] = pv;
      p01 = (unsigned int)f2bf(w0.y) | ((unsigned int)f2bf(w1.y) << 16);
      p23 = (unsigned int)f2bf(w2.y) | ((unsigned int)f2bf(w3.y) << 16);
      pv.x = p01; pv.y = p23;
      *(uint2*)&Bs[(bc + 1) * 40 + bk] = pv;
      p01 = (unsigned int)f2bf(w0.z) | ((unsigned int)f2bf(w1.z) << 16);
      p23 = (unsigned int)f2bf(w2.z) | ((unsigned int)f2bf(w3.z) << 16);
      pv.x = p01; pv.y = p23;
      *(uint2*)&Bs[(bc + 2) * 40 + bk] = pv;
      p01 = (unsigned int)f2bf(w0.w) | ((unsigned int)f2bf(w1.w) << 16);
      p23 = (unsigned int)f2bf(w2.w) | ((unsigned int)f2bf(w3.w) << 16);
      pv.x = p01; pv.y = pv.y = p23;
      *(uint2*)&Bs[(bc + 3) * 40 + bk] = pv;
    }

    __syncthreads();

    bf16x8 af[4], bfr[4];
#pragma unroll
    for (int m = 0; m < 4; ++m)
      af[m] = *(const bf16x8*)&As[(wr + m * 16 + fr) * 40 + fq * 8];
#pragma unroll
    for (int n = 0; n < 4; ++n)
      bfr[n] = *(const bf16x8*)&Bs[(wc + n * 16 + fr) * 40 + fq * 8];
#pragma unroll
    for (int m = 0; m < 4; ++m)
#pragma unroll
      for (int n = 0; n < 4; ++n)
        acc[m][n] = __builtin_amdgcn_mfma_f32_16x16x32_bf16(af[m], bfr[n], acc[m][n], 0, 0, 0);
  }

  if (PASS == 1) {
#pragma unroll
    for (int n = 0; n < 4; ++n) {
      int col = ct * 128 + wc + n * 16 + fr;
      float b1v = bias[(size_t)e * NS + col];
#pragma unroll
      for (int m = 0; m < 4; ++m) {
#pragma unroll
        for (int r = 0; r < 4; ++r) {
          int lrow = wr + m * 16 + fq * 4 + r;
          if (lrow < rowsvalid) {
            float v = acc[m][n][r] + b1v;
            v = 0.5f * v * (1.f + erff(v * 0.70710678118654752440f));
            Hmat[(size_t)(gbase + rt * 128 + lrow) * HID + col] = f2bf(v);
          }
        }
      }
    }
  } else {
    float b2v[4];
#pragma unroll
    for (int n = 0; n < 4; ++n)
      b2v[n] = bias[(size_t)e * NS + ct * 128 + wc + n * 16 + fr];
#pragma unroll
    for (int m = 0; m < 4; ++m) {
#pragma unroll
      for (int r = 0; r < 4; ++r) {
        int lrow = wr + m * 16 + fq * 4 + r;
        if (lrow < rowsvalid) {
          int g = gbase + rt * 128 + lrow;
          int ent = pairmap[g];
          int tok = ent >> 1;
          float s = score[ent];
#pragma unroll
          for (int n = 0; n < 4; ++n) {
            int col = ct * 128 + wc + n * 16 + fr;
            atomicAdd(&out[(size_t)tok * DIM + col], s * (acc[m][n][r] + b2v[n]));
          }
        }
      }
    }
  }
}

// ================= fallback (round-0 fp32 path, used only if ws too small) =================
__global__ __launch_bounds__(256) void moe_mlp_kernel(
    const float* __restrict__ x, const float* __restrict__ W1, const float* __restrict__ b1,
    const float* __restrict__ W2, const float* __restrict__ b2,
    const int* __restrict__ count, const int* __restrict__ lists,
    const float* __restrict__ topk_score, float* __restrict__ pairout,
    float* __restrict__ out, int use_pairout, int N) {
  const int e = blockIdx.y;
  const int nc = count[e];
  const int base = blockIdx.x * TN;
  if (base >= nc) return;
  __shared__ float Xs[DC][18];
  __shared__ float W1s[DC][HC];
  __shared__ float Hs[TN][HC];
  __shared__ int toks[TN];
  __shared__ int kks[TN];
  __shared__ int actv[TN];
  const int tid = threadIdx.x;
  if (tid < TN) {
    int i = base + tid;
    int ent = lists[(size_t)e * N + ((i < nc) ? i : base)];
    toks[tid] = ent >> 1; kks[tid] = ent & 1; actv[tid] = (i < nc) ? 1 : 0;
  }
  __syncthreads();
  float Oacc[TN][4];
#pragma unroll
  for (int t = 0; t < TN; ++t) { Oacc[t][0]=0.f;Oacc[t][1]=0.f;Oacc[t][2]=0.f;Oacc[t][3]=0.f; }
  const float* W1e = W1 + (size_t)e * DIM * HID;
  const float* W2e = W2 + (size_t)e * HID * DIM;
  const int h4 = (tid & 31) * 4;
  const int t0 = (tid >> 5) * 2;
  const int ldt = tid >> 4;
  const int lddq = (tid & 15) * 4;
  for (int h0 = 0; h0 < HID; h0 += HC) {
    float ha[2][4];
#pragma unroll
    for (int tt = 0; tt < 2; ++tt) { ha[tt][0]=0.f;ha[tt][1]=0.f;ha[tt][2]=0.f;ha[tt][3]=0.f; }
    for (int d0 = 0; d0 < DIM; d0 += DC) {
      float4 xv4 = *(const float4*)(x + (size_t)toks[ldt] * DIM + d0 + lddq);
      Xs[lddq + 0][ldt] = xv4.x; Xs[lddq + 1][ldt] = xv4.y;
      Xs[lddq + 2][ldt] = xv4.z; Xs[lddq + 3][ldt] = xv4.w;
      {
        const int wrow = tid >> 5; const int wcol = (tid & 31) * 4;
#pragma unroll
        for (int p = 0; p < 8; ++p) {
          int dd = wrow + p * 8;
          *(float4*)&W1s[dd][wcol] = *(const float4*)(W1e + (size_t)(d0 + dd) * HID + h0 + wcol);
        }
      }
      __syncthreads();
#pragma unroll
      for (int dd = 0; dd < DC; ++dd) {
        float2 xv = *(const float2*)&Xs[dd][t0];
        float4 wv = *(const float4*)&W1s[dd][h4];
        ha[0][0]+=xv.x*wv.x; ha[0][1]+=xv.x*wv.y; ha[0][2]+=xv.x*wv.z; ha[0][3]+=xv.x*wv.w;
        ha[1][0]+=xv.y*wv.x; ha[1][1]+=xv.y*wv.y; ha[1][2]+=xv.y*wv.z; ha[1][3]+=xv.y*wv.w;
      }
      __syncthreads();
    }
    {
      float4 b1v = *(const float4*)(b1 + (size_t)e * HID + h0 + h4);
#pragma unroll
      for (int tt = 0; tt < 2; ++tt) {
        float v0 = ha[tt][0] + b1v.x, v1 = ha[tt][1] + b1v.y;
        float v2 = ha[tt][2] + b1v.z, v3 = ha[tt][3] + b1v.w;
        float4 g;
        g.x = 0.5f*v0*(1.f+erff(v0*0.70710678f)); g.y = 0.5f*v1*(1.f+erff(v1*0.70710678f));
        g.z = 0.5f*v2*(1.f+erff(v2*0.70710678f)); g.w = 0.5f*v3*(1.f+erff(v3*0.70710678f));
        *(float4*)&Hs[t0 + tt][h4] = g;
      }
    }
    __syncthreads();
    const float* w2p = W2e + (size_t)h0 * DIM + tid * 4;
#pragma unroll 2
    for (int h = 0; h < HC; ++h) {
      float4 wv = *(const float4*)w2p; w2p += DIM;
#pragma unroll
      for (int t = 0; t < TN; ++t) {
        float hv = Hs[t][h];
        Oacc[t][0]+=hv*wv.x; Oacc[t][1]+=hv*wv.y; Oacc[t][2]+=hv*wv.z; Oacc[t][3]+=hv*wv.w;
      }
    }
    __syncthreads();
  }
  const int c4 = tid * 4;
  float4 b2v = *(const float4*)(b2 + (size_t)e * DIM + c4);
#pragma unroll
  for (int t = 0; t < TN; ++t) {
    if (actv[t]) {
      float o0=Oacc[t][0]+b2v.x, o1=Oacc[t][1]+b2v.y, o2=Oacc[t][2]+b2v.z, o3=Oacc[t][3]+b2v.w;
      int tok = toks[t], k = kks[t];
      if (use_pairout) {
        *(float4*)(pairout + ((size_t)tok * TOPK + k) * DIM + c4) = make_float4(o0,o1,o2,o3);
      } else {
        float s = topk_score[tok * TOPK + k];
        float* op = out + (size_t)tok * DIM + c4;
        atomicAdd(op+0, s*o0); atomicAdd(op+1, s*o1); atomicAdd(op+2, s*o2); atomicAdd(op+3, s*o3);
      }
    }
  }
}

__global__ void combine_kernel(const float* __restrict__ pairout,
                               const float* __restrict__ topk_score,
                               float* __restrict__ out, int N) {
  int idx = blockIdx.x * blockDim.x + threadIdx.x;
  int total = N * (DIM / 4);
  if (idx >= total) return;
  int n = idx / (DIM / 4);
  int c4 = (idx % (DIM / 4)) * 4;
  float s0 = topk_score[n * TOPK + 0];
  float s1 = topk_score[n * TOPK + 1];
  float4 p0 = *(const float4*)(pairout + ((size_t)n * TOPK + 0) * DIM + c4);
  float4 p1 = *(const float4*)(pairout + ((size_t)n * TOPK + 1) * DIM + c4);
  float4 o;
  o.x = s0*p0.x + s1*p1.x; o.y = s0*p0.y + s1*p1.y;
  o.z = s0*p0.z + s1*p1.z; o.w = s0*p0.w + s1*p1.w;
  *(float4*)(out + (size_t)n * DIM + c4) = o;
}

extern "C" void kernel_launch(void* const* d_in, const int* in_sizes, int n_in,
                              void* d_out, int out_size, void* d_ws, size_t ws_size,
                              hipStream_t stream) {
  const float* x  = (const float*)d_in[0];
  const float* W1 = (const float*)d_in[1];
  const float* b1 = (const float*)d_in[2];
  const float* W2 = (const float*)d_in[3];
  const float* b2 = (const float*)d_in[4];
  const float* Wg = (const float*)d_in[5];
  const float* bg = (const float*)d_in[6];
  float* out = (float*)d_out;
  const int N  = in_sizes[0] / DIM;  // tokens (4096)
  const int NP = N * TOPK;           // pairs (8192)

  char* ws = (char*)d_ws;
  size_t off = 0;
  auto alloc = [&](size_t bytes) -> void* {
    void* p = ws + off;
    off = (off + bytes + 255) & ~(size_t)255;
    return p;
  };
  int*   count      = (int*)alloc(NEXP * sizeof(int));
  int*   offsets    = (int*)alloc((NEXP + 1) * sizeof(int));
  float* topk_score = (float*)alloc((size_t)NP * sizeof(float));
  int*   lists      = (int*)alloc((size_t)NEXP * N * sizeof(int));
  int*   pairmap    = (int*)alloc((size_t)NP * sizeof(int));
  size_t off_small = off;
  unsigned short* Xg   = (unsigned short*)alloc((size_t)NP * DIM * sizeof(unsigned short));
  unsigned short* Hmat = (unsigned short*)alloc((size_t)NP * HID * sizeof(unsigned short));
  size_t need_fast = off;

  hipMemsetAsync(count, 0, NEXP * sizeof(int), stream);
  gate_kernel<<<N, 64, 0, stream>>>(x, Wg, bg, topk_score, count, lists, N);

  if (ws_size >= need_fast) {
    offsets_kernel<<<1, 64, 0, stream>>>(count, offsets);
    gather_kernel<<<NP, DIM / 4, 0, stream>>>(x, offsets, lists, Xg, pairmap, N);
    hipMemsetAsync(out, 0, (size_t)out_size * sizeof(float), stream);
    int RT = (N + 127) / 128;
    dim3 g1(RT, HID / 128, NEXP);
    moe_gemm<1><<<g1, 256, 0, stream>>>(Xg, W1, b1, offsets, pairmap, topk_score, Hmat, out);
    dim3 g2(RT, DIM / 128, NEXP);
    moe_gemm<2><<<g2, 256, 0, stream>>>(Hmat, W2, b2, offsets, pairmap, topk_score, Hmat, out);
  } else {
    // fallback: round-0 fp32 path
    float* pairout = (float*)(ws + off_small);
    size_t need_fb = off_small + (size_t)NP * DIM * sizeof(float);
    int use_pairout = (ws_size >= need_fb) ? 1 : 0;
    if (!use_pairout) hipMemsetAsync(out, 0, (size_t)out_size * sizeof(float), stream);
    dim3 grid((N + TN - 1) / TN, NEXP);
    moe_mlp_kernel<<<grid, 256, 0, stream>>>(x, W1, b1, W2, b2, count, lists,
                                             topk_score, pairout, out, use_pairout, N);
    if (use_pairout) {
      int total = N * (DIM / 4);
      combine_kernel<<<(total + 255) / 256, 256, 0, stream>>>(pairout, topk_score, out, N);
    }
  }
}

// Round 3
// 857.679 us; speedup vs baseline: 6.9866x; 1.6120x over previous
//
#include <hip/hip_runtime.h>
#include <math.h>

#define DIM  1024   // hidden dim D
#define NEXP 8      // experts
#define HID  4096   // expert hidden H
#define TOPK 2

typedef __attribute__((ext_vector_type(8))) short bf16x8;
typedef __attribute__((ext_vector_type(4))) float f32x4;

__device__ inline unsigned short f2bf(float f) {
  union { float f; unsigned int u; } v; v.f = f;
  unsigned int u = v.u;
  return (unsigned short)((u + 0x7FFFu + ((u >> 16) & 1u)) >> 16);
}

__device__ inline void load_lds16(const void* g, void* l) {
  __builtin_amdgcn_global_load_lds(
      (const __attribute__((address_space(1))) void*)g,
      (__attribute__((address_space(3))) void*)l, 16, 0, 0);
}

// ---------------- gate: logits -> softmax -> top2 -> routing lists ----------------
__global__ void gate_kernel(const float* __restrict__ x,
                            const float* __restrict__ Wg,
                            const float* __restrict__ bg,
                            float* __restrict__ topk_score,
                            int* __restrict__ count,
                            int* __restrict__ lists,
                            int N) {
  int n = blockIdx.x;
  if (n >= N) return;
  int lane = threadIdx.x;
  float acc[NEXP];
#pragma unroll
  for (int e = 0; e < NEXP; ++e) acc[e] = 0.f;
  const float* xr = x + (size_t)n * DIM;
  for (int d = lane; d < DIM; d += 64) {
    float xv = xr[d];
    const float* w = Wg + (size_t)d * NEXP;
#pragma unroll
    for (int e = 0; e < NEXP; ++e) acc[e] += xv * w[e];
  }
#pragma unroll
  for (int off = 32; off > 0; off >>= 1) {
#pragma unroll
    for (int e = 0; e < NEXP; ++e) acc[e] += __shfl_xor(acc[e], off, 64);
  }
  if (lane == 0) {
    float l[NEXP];
#pragma unroll
    for (int e = 0; e < NEXP; ++e) l[e] = acc[e] + bg[e];
    float m = l[0];
#pragma unroll
    for (int e = 1; e < NEXP; ++e) m = fmaxf(m, l[e]);
    float p[NEXP];
    float s = 0.f;
#pragma unroll
    for (int e = 0; e < NEXP; ++e) { p[e] = expf(l[e] - m); s += p[e]; }
    int i0 = 0;
#pragma unroll
    for (int e = 1; e < NEXP; ++e) if (l[e] > l[i0]) i0 = e;
    int i1 = (i0 == 0) ? 1 : 0;
#pragma unroll
    for (int e = 0; e < NEXP; ++e) if (e != i0 && l[e] > l[i1]) i1 = e;
    float inv = 1.f / s;
    topk_score[n * TOPK + 0] = p[i0] * inv;
    topk_score[n * TOPK + 1] = p[i1] * inv;
    int pos0 = atomicAdd(&count[i0], 1);
    lists[(size_t)i0 * N + pos0] = n * TOPK + 0;
    int pos1 = atomicAdd(&count[i1], 1);
    lists[(size_t)i1 * N + pos1] = n * TOPK + 1;
  }
}

__global__ void offsets_kernel(const int* __restrict__ count, int* __restrict__ offsets) {
  if (threadIdx.x == 0 && blockIdx.x == 0) {
    int s = 0;
    for (int e = 0; e < NEXP; ++e) { offsets[e] = s; s += count[e]; }
    offsets[NEXP] = s;
  }
}

// gather token rows (sorted by expert) into bf16 Xg; record pair mapping
__global__ void gather_kernel(const float* __restrict__ x,
                              const int* __restrict__ offsets,
                              const int* __restrict__ lists,
                              unsigned short* __restrict__ Xg,
                              int* __restrict__ pairmap,
                              int N) {
  int g = blockIdx.x;
  int e = 0;
  while (e < NEXP - 1 && g >= offsets[e + 1]) ++e;
  int i = g - offsets[e];
  int ent = lists[(size_t)e * N + i];
  int tok = ent >> 1;
  if (threadIdx.x == 0) pairmap[g] = ent;
  float4 v = *((const float4*)(x + (size_t)tok * DIM) + threadIdx.x);
  ushort4 o;
  o.x = f2bf(v.x); o.y = f2bf(v.y); o.z = f2bf(v.z); o.w = f2bf(v.w);
  *((ushort4*)(Xg + (size_t)g * DIM) + threadIdx.x) = o;
}

// ------------- transpose-convert: src [e][R][C] fp32 -> dst [e][C][R] bf16 -------------
__global__ __launch_bounds__(256) void transpose_convert(
    const float* __restrict__ src, unsigned short* __restrict__ dst, int R, int C) {
  const int e = blockIdx.z;
  src += (size_t)e * R * C;
  dst += (size_t)e * R * C;
  const int r0 = blockIdx.x * 64, c0 = blockIdx.y * 64;
  __shared__ unsigned short Ts[64][68];
  const int t = threadIdx.x;
  const int rr = t >> 4, cc = (t & 15) * 4;
#pragma unroll
  for (int p = 0; p < 4; ++p) {
    int r = rr + p * 16;
    float4 v = *(const float4*)(src + (size_t)(r0 + r) * C + c0 + cc);
    Ts[cc + 0][r] = f2bf(v.x);
    Ts[cc + 1][r] = f2bf(v.y);
    Ts[cc + 2][r] = f2bf(v.z);
    Ts[cc + 3][r] = f2bf(v.w);
  }
  __syncthreads();
  const int cr = t >> 3, rq = (t & 7) * 8;
#pragma unroll
  for (int p = 0; p < 2; ++p) {
    int c = cr + p * 32;
    ushort4 a = *(ushort4*)&Ts[c][rq];
    ushort4 b = *(ushort4*)&Ts[c][rq + 4];
    *(ushort4*)(dst + (size_t)(c0 + c) * R + r0 + rq) = a;
    *(ushort4*)(dst + (size_t)(c0 + c) * R + r0 + rq + 4) = b;
  }
}

// ---------------- grouped bf16 GEMM, 128x128 tile, BK=64, global_load_lds + XOR swizzle ----------------
// PASS 1: Hmat = gelu(Xg * W1T^T + b1)   (A=Xg [g][1024], B=W1T [e][4096][1024])
// PASS 2: out[tok] += score * (Hmat * W2T^T + b2)
template <int PASS>
__global__ __launch_bounds__(256, 3) void moe_gemm2(
    const unsigned short* __restrict__ Asrc,
    const unsigned short* __restrict__ Bt,
    const float* __restrict__ bias,
    const int* __restrict__ offsets,
    const int* __restrict__ pairmap,
    const float* __restrict__ score,
    unsigned short* __restrict__ Hmat,
    float* __restrict__ out) {
  constexpr int K  = (PASS == 1) ? DIM : HID;
  constexpr int NS = (PASS == 1) ? HID : DIM;
  const int e = blockIdx.z;
  const int gbase = offsets[e];
  const int nc = offsets[e + 1] - gbase;
  const int rt = blockIdx.x;
  if (rt * 128 >= nc) return;
  const int rowsvalid = min(128, nc - rt * 128);
  const int ct = blockIdx.y;

  __shared__ unsigned short As[128 * 64];
  __shared__ unsigned short Bs[128 * 64];

  const int tid  = threadIdx.x;
  const int lane = tid & 63;
  const int wid  = tid >> 6;
  const int wr = (wid >> 1) * 64;
  const int wc = (wid & 1) * 64;
  const int fr = lane & 15;
  const int fq = lane >> 4;

  f32x4 acc[4][4];
#pragma unroll
  for (int m = 0; m < 4; ++m)
#pragma unroll
    for (int n = 0; n < 4; ++n) acc[m][n] = (f32x4){0.f, 0.f, 0.f, 0.f};

  // staging: thread -> (row srow within 32-row issue, 16B unit), source XOR-pre-swizzled
  const int srow  = tid >> 3;                 // 0..31
  const int sunit = tid & 7;                  // 0..7 (16B units in 128B row)
  const int sswz  = sunit ^ (srow & 7);       // involution; (srow+32*is)&7 == srow&7
  const unsigned short* Ab = Asrc + (size_t)(gbase + rt * 128) * K;
  const unsigned short* Bb = Bt + (size_t)e * NS * K + (size_t)ct * 128 * K;

  for (int k0 = 0; k0 < K; k0 += 64) {
    __syncthreads();  // previous iteration's fragment reads complete
#pragma unroll
    for (int is = 0; is < 4; ++is) {
      int r = is * 32 + srow;
      load_lds16(Ab + (size_t)r * K + k0 + sswz * 8, (char*)As + is * 4096 + tid * 16);
      load_lds16(Bb + (size_t)r * K + k0 + sswz * 8, (char*)Bs + is * 4096 + tid * 16);
    }
    __syncthreads();  // drains vmcnt: LDS tiles ready

    bf16x8 af[2][4], bfv[2][4];
#pragma unroll
    for (int kk = 0; kk < 2; ++kk) {
      const int au = ((kk * 4 + fq) ^ (fr & 7)) * 8;  // swizzled unit -> elem offset
#pragma unroll
      for (int m = 0; m < 4; ++m)
        af[kk][m] = *(const bf16x8*)&As[(wr + m * 16 + fr) * 64 + au];
#pragma unroll
      for (int n = 0; n < 4; ++n)
        bfv[kk][n] = *(const bf16x8*)&Bs[(wc + n * 16 + fr) * 64 + au];
    }
#pragma unroll
    for (int kk = 0; kk < 2; ++kk)
#pragma unroll
      for (int m = 0; m < 4; ++m)
#pragma unroll
        for (int n = 0; n < 4; ++n)
          acc[m][n] = __builtin_amdgcn_mfma_f32_16x16x32_bf16(af[kk][m], bfv[kk][n], acc[m][n], 0, 0, 0);
  }

  if (PASS == 1) {
#pragma unroll
    for (int n = 0; n < 4; ++n) {
      const int col = ct * 128 + wc + n * 16 + fr;
      const float b1v = bias[(size_t)e * NS + col];
#pragma unroll
      for (int m = 0; m < 4; ++m) {
#pragma unroll
        for (int r = 0; r < 4; ++r) {
          const int lrow = wr + m * 16 + fq * 4 + r;
          if (lrow < rowsvalid) {
            float v = acc[m][n][r] + b1v;
            v = 0.5f * v * (1.f + erff(v * 0.70710678118654752440f));
            Hmat[(size_t)(gbase + rt * 128 + lrow) * HID + col] = f2bf(v);
          }
        }
      }
    }
  } else {
    float b2v[4];
#pragma unroll
    for (int n = 0; n < 4; ++n)
      b2v[n] = bias[(size_t)e * NS + ct * 128 + wc + n * 16 + fr];
#pragma unroll
    for (int m = 0; m < 4; ++m) {
#pragma unroll
      for (int r = 0; r < 4; ++r) {
        const int lrow = wr + m * 16 + fq * 4 + r;
        if (lrow < rowsvalid) {
          const int g = gbase + rt * 128 + lrow;
          const int ent = pairmap[g];
          const int tok = ent >> 1;
          const float s = score[ent];
#pragma unroll
          for (int n = 0; n < 4; ++n) {
            const int col = ct * 128 + wc + n * 16 + fr;
            atomicAdd(&out[(size_t)tok * DIM + col], s * (acc[m][n][r] + b2v[n]));
          }
        }
      }
    }
  }
}

// ============== fallback: round-1 GEMM (fp32 weights converted in-loop) ==============
template <int PASS>
__global__ __launch_bounds__(256) void moe_gemm(
    const unsigned short* __restrict__ Asrc,
    const float* __restrict__ Bsrc,
    const float* __restrict__ bias,
    const int* __restrict__ offsets,
    const int* __restrict__ pairmap,
    const float* __restrict__ score,
    unsigned short* __restrict__ Hmat,
    float* __restrict__ out) {
  constexpr int K  = (PASS == 1) ? DIM : HID;
  constexpr int NS = (PASS == 1) ? HID : DIM;
  const int e = blockIdx.z;
  const int gbase = offsets[e];
  const int nc = offsets[e + 1] - gbase;
  const int rt = blockIdx.x;
  if (rt * 128 >= nc) return;
  const int rowsvalid = min(128, nc - rt * 128);
  const int ct = blockIdx.y;
  __shared__ unsigned short As[128 * 40];
  __shared__ unsigned short Bs[128 * 40];
  const int tid  = threadIdx.x;
  const int lane = tid & 63;
  const int wid  = tid >> 6;
  const int wr = (wid >> 1) * 64;
  const int wc = (wid & 1) * 64;
  const int fr = lane & 15;
  const int fq = lane >> 4;
  f32x4 acc[4][4];
#pragma unroll
  for (int m = 0; m < 4; ++m)
#pragma unroll
    for (int n = 0; n < 4; ++n) acc[m][n] = (f32x4){0.f, 0.f, 0.f, 0.f};
  const int ar = tid >> 1;
  const int ak = (tid & 1) * 16;
  int arow = rt * 128 + ((ar < rowsvalid) ? ar : 0);
  const unsigned short* Aptr = Asrc + (size_t)(gbase + arow) * K + ak;
  const int bc = (tid & 31) * 4;
  const int bk = (tid >> 5) * 4;
  const float* Bptr = Bsrc + (size_t)e * K * NS + (size_t)bk * NS + ct * 128 + bc;
  for (int k0 = 0; k0 < K; k0 += 32) {
    uint4 av0 = *(const uint4*)(Aptr + k0);
    uint4 av1 = *(const uint4*)(Aptr + k0 + 8);
    const float* bp = Bptr + (size_t)k0 * NS;
    float4 w0 = *(const float4*)(bp);
    float4 w1 = *(const float4*)(bp + NS);
    float4 w2 = *(const float4*)(bp + 2 * NS);
    float4 w3 = *(const float4*)(bp + 3 * NS);
    __syncthreads();
    *(uint4*)&As[ar * 40 + ak]     = av0;
    *(uint4*)&As[ar * 40 + ak + 8] = av1;
    {
      uint2 pv;
      pv.x = (unsigned int)f2bf(w0.x) | ((unsigned int)f2bf(w1.x) << 16);
      pv.y = (unsigned int)f2bf(w2.x) | ((unsigned int)f2bf(w3.x) << 16);
      *(uint2*)&Bs[(bc + 0) * 40 + bk] = pv;
      pv.x = (unsigned int)f2bf(w0.y) | ((unsigned int)f2bf(w1.y) << 16);
      pv.y = (unsigned int)f2bf(w2.y) | ((unsigned int)f2bf(w3.y) << 16);
      *(uint2*)&Bs[(bc + 1) * 40 + bk] = pv;
      pv.x = (unsigned int)f2bf(w0.z) | ((unsigned int)f2bf(w1.z) << 16);
      pv.y = (unsigned int)f2bf(w2.z) | ((unsigned int)f2bf(w3.z) << 16);
      *(uint2*)&Bs[(bc + 2) * 40 + bk] = pv;
      pv.x = (unsigned int)f2bf(w0.w) | ((unsigned int)f2bf(w1.w) << 16);
      pv.y = (unsigned int)f2bf(w2.w) | ((unsigned int)f2bf(w3.w) << 16);
      *(uint2*)&Bs[(bc + 3) * 40 + bk] = pv;
    }
    __syncthreads();
    bf16x8 af[4], bfr[4];
#pragma unroll
    for (int m = 0; m < 4; ++m)
      af[m] = *(const bf16x8*)&As[(wr + m * 16 + fr) * 40 + fq * 8];
#pragma unroll
    for (int n = 0; n < 4; ++n)
      bfr[n] = *(const bf16x8*)&Bs[(wc + n * 16 + fr) * 40 + fq * 8];
#pragma unroll
    for (int m = 0; m < 4; ++m)
#pragma unroll
      for (int n = 0; n < 4; ++n)
        acc[m][n] = __builtin_amdgcn_mfma_f32_16x16x32_bf16(af[m], bfr[n], acc[m][n], 0, 0, 0);
  }
  if (PASS == 1) {
#pragma unroll
    for (int n = 0; n < 4; ++n) {
      int col = ct * 128 + wc + n * 16 + fr;
      float b1v = bias[(size_t)e * NS + col];
#pragma unroll
      for (int m = 0; m < 4; ++m) {
#pragma unroll
        for (int r = 0; r < 4; ++r) {
          int lrow = wr + m * 16 + fq * 4 + r;
          if (lrow < rowsvalid) {
            float v = acc[m][n][r] + b1v;
            v = 0.5f * v * (1.f + erff(v * 0.70710678118654752440f));
            Hmat[(size_t)(gbase + rt * 128 + lrow) * HID + col] = f2bf(v);
          }
        }
      }
    }
  } else {
    float b2v[4];
#pragma unroll
    for (int n = 0; n < 4; ++n)
      b2v[n] = bias[(size_t)e * NS + ct * 128 + wc + n * 16 + fr];
#pragma unroll
    for (int m = 0; m < 4; ++m) {
#pragma unroll
      for (int r = 0; r < 4; ++r) {
        int lrow = wr + m * 16 + fq * 4 + r;
        if (lrow < rowsvalid) {
          int g = gbase + rt * 128 + lrow;
          int ent = pairmap[g];
          int tok = ent >> 1;
          float s = score[ent];
#pragma unroll
          for (int n = 0; n < 4; ++n) {
            int col = ct * 128 + wc + n * 16 + fr;
            atomicAdd(&out[(size_t)tok * DIM + col], s * (acc[m][n][r] + b2v[n]));
          }
        }
      }
    }
  }
}

extern "C" void kernel_launch(void* const* d_in, const int* in_sizes, int n_in,
                              void* d_out, int out_size, void* d_ws, size_t ws_size,
                              hipStream_t stream) {
  const float* x  = (const float*)d_in[0];
  const float* W1 = (const float*)d_in[1];
  const float* b1 = (const float*)d_in[2];
  const float* W2 = (const float*)d_in[3];
  const float* b2 = (const float*)d_in[4];
  const float* Wg = (const float*)d_in[5];
  const float* bg = (const float*)d_in[6];
  float* out = (float*)d_out;
  const int N  = in_sizes[0] / DIM;  // tokens (4096)
  const int NP = N * TOPK;           // pairs (8192)

  char* ws = (char*)d_ws;
  size_t off = 0;
  auto alloc = [&](size_t bytes) -> void* {
    void* p = ws + off;
    off = (off + bytes + 255) & ~(size_t)255;
    return p;
  };
  int*   count      = (int*)alloc(NEXP * sizeof(int));
  int*   offsets    = (int*)alloc((NEXP + 1) * sizeof(int));
  float* topk_score = (float*)alloc((size_t)NP * sizeof(float));
  int*   lists      = (int*)alloc((size_t)NEXP * N * sizeof(int));
  int*   pairmap    = (int*)alloc((size_t)NP * sizeof(int));
  // padded by 128 rows: GEMM A-staging reads past the last valid row of a tile
  unsigned short* Xg   = (unsigned short*)alloc((size_t)(NP + 128) * DIM * sizeof(unsigned short));
  unsigned short* Hmat = (unsigned short*)alloc((size_t)(NP + 128) * HID * sizeof(unsigned short));
  size_t need_mid = off;
  unsigned short* W1T = (unsigned short*)alloc((size_t)NEXP * DIM * HID * sizeof(unsigned short));
  unsigned short* W2T = (unsigned short*)alloc((size_t)NEXP * HID * DIM * sizeof(unsigned short));
  size_t need_full = off;

  hipMemsetAsync(count, 0, NEXP * sizeof(int), stream);
  gate_kernel<<<N, 64, 0, stream>>>(x, Wg, bg, topk_score, count, lists, N);
  offsets_kernel<<<1, 64, 0, stream>>>(count, offsets);
  gather_kernel<<<NP, DIM / 4, 0, stream>>>(x, offsets, lists, Xg, pairmap, N);
  hipMemsetAsync(out, 0, (size_t)out_size * sizeof(float), stream);

  const int RT = (N + 127) / 128;
  if (ws_size >= need_full) {
    // one-time weight transpose-convert to bf16 K-contiguous
    dim3 tg1(DIM / 64, HID / 64, NEXP);
    transpose_convert<<<tg1, 256, 0, stream>>>(W1, W1T, DIM, HID);
    dim3 tg2(HID / 64, DIM / 64, NEXP);
    transpose_convert<<<tg2, 256, 0, stream>>>(W2, W2T, HID, DIM);

    dim3 g1(RT, HID / 128, NEXP);
    moe_gemm2<1><<<g1, 256, 0, stream>>>(Xg, W1T, b1, offsets, pairmap, topk_score, Hmat, out);
    dim3 g2(RT, DIM / 128, NEXP);
    moe_gemm2<2><<<g2, 256, 0, stream>>>(Hmat, W2T, b2, offsets, pairmap, topk_score, Hmat, out);
  } else {
    (void)need_mid;
    dim3 g1(RT, HID / 128, NEXP);
    moe_gemm<1><<<g1, 256, 0, stream>>>(Xg, W1, b1, offsets, pairmap, topk_score, Hmat, out);
    dim3 g2(RT, DIM / 128, NEXP);
    moe_gemm<2><<<g2, 256, 0, stream>>>(Hmat, W2, b2, offsets, pairmap, topk_score, Hmat, out);
  }
}

// Round 4
// 735.746 us; speedup vs baseline: 8.1445x; 1.1657x over previous
//
#include <hip/hip_runtime.h>
#include <math.h>

#define DIM  1024   // hidden dim D
#define NEXP 8      // experts
#define HID  4096   // expert hidden H
#define TOPK 2

typedef __attribute__((ext_vector_type(8))) short bf16x8;
typedef __attribute__((ext_vector_type(4))) float f32x4;

__device__ inline unsigned short f2bf(float f) {
  union { float f; unsigned int u; } v; v.f = f;
  unsigned int u = v.u;
  return (unsigned short)((u + 0x7FFFu + ((u >> 16) & 1u)) >> 16);
}

__device__ inline void load_lds16(const void* g, void* l) {
  __builtin_amdgcn_global_load_lds(
      (const __attribute__((address_space(1))) void*)g,
      (__attribute__((address_space(3))) void*)l, 16, 0, 0);
}

// ---------------- gate: logits -> softmax -> top2 -> routing lists ----------------
__global__ void gate_kernel(const float* __restrict__ x,
                            const float* __restrict__ Wg,
                            const float* __restrict__ bg,
                            float* __restrict__ topk_score,
                            int* __restrict__ count,
                            int* __restrict__ lists,
                            int N) {
  int n = blockIdx.x;
  if (n >= N) return;
  int lane = threadIdx.x;
  float acc[NEXP];
#pragma unroll
  for (int e = 0; e < NEXP; ++e) acc[e] = 0.f;
  const float* xr = x + (size_t)n * DIM;
  for (int d = lane; d < DIM; d += 64) {
    float xv = xr[d];
    const float* w = Wg + (size_t)d * NEXP;
#pragma unroll
    for (int e = 0; e < NEXP; ++e) acc[e] += xv * w[e];
  }
#pragma unroll
  for (int off = 32; off > 0; off >>= 1) {
#pragma unroll
    for (int e = 0; e < NEXP; ++e) acc[e] += __shfl_xor(acc[e], off, 64);
  }
  if (lane == 0) {
    float l[NEXP];
#pragma unroll
    for (int e = 0; e < NEXP; ++e) l[e] = acc[e] + bg[e];
    float m = l[0];
#pragma unroll
    for (int e = 1; e < NEXP; ++e) m = fmaxf(m, l[e]);
    float p[NEXP];
    float s = 0.f;
#pragma unroll
    for (int e = 0; e < NEXP; ++e) { p[e] = expf(l[e] - m); s += p[e]; }
    int i0 = 0;
#pragma unroll
    for (int e = 1; e < NEXP; ++e) if (l[e] > l[i0]) i0 = e;
    int i1 = (i0 == 0) ? 1 : 0;
#pragma unroll
    for (int e = 0; e < NEXP; ++e) if (e != i0 && l[e] > l[i1]) i1 = e;
    float inv = 1.f / s;
    topk_score[n * TOPK + 0] = p[i0] * inv;
    topk_score[n * TOPK + 1] = p[i1] * inv;
    int pos0 = atomicAdd(&count[i0], 1);
    lists[(size_t)i0 * N + pos0] = n * TOPK + 0;
    int pos1 = atomicAdd(&count[i1], 1);
    lists[(size_t)i1 * N + pos1] = n * TOPK + 1;
  }
}

// offsets + flattened row-tile table (kills dead blocks)
__global__ void offsets_kernel(const int* __restrict__ count, int* __restrict__ offsets,
                               int* __restrict__ tiles, int* __restrict__ ntiles) {
  if (threadIdx.x == 0 && blockIdx.x == 0) {
    int s = 0, nt = 0;
    for (int e = 0; e < NEXP; ++e) {
      offsets[e] = s;
      int c = count[e];
      s += c;
      int rts = (c + 127) >> 7;
      for (int i = 0; i < rts; ++i) tiles[nt++] = (e << 16) | i;
    }
    offsets[NEXP] = s;
    ntiles[0] = nt;
  }
}

// gather token rows (sorted by expert) into bf16 Xg; record pair mapping
__global__ void gather_kernel(const float* __restrict__ x,
                              const int* __restrict__ offsets,
                              const int* __restrict__ lists,
                              unsigned short* __restrict__ Xg,
                              int* __restrict__ pairmap,
                              int N) {
  int g = blockIdx.x;
  int e = 0;
  while (e < NEXP - 1 && g >= offsets[e + 1]) ++e;
  int i = g - offsets[e];
  int ent = lists[(size_t)e * N + i];
  int tok = ent >> 1;
  if (threadIdx.x == 0) pairmap[g] = ent;
  float4 v = *((const float4*)(x + (size_t)tok * DIM) + threadIdx.x);
  ushort4 o;
  o.x = f2bf(v.x); o.y = f2bf(v.y); o.z = f2bf(v.z); o.w = f2bf(v.w);
  *((ushort4*)(Xg + (size_t)g * DIM) + threadIdx.x) = o;
}

// ------------- transpose-convert: src [e][R][C] fp32 -> dst [e][C][R] bf16 -------------
__global__ __launch_bounds__(256) void transpose_convert(
    const float* __restrict__ src, unsigned short* __restrict__ dst, int R, int C) {
  const int e = blockIdx.z;
  src += (size_t)e * R * C;
  dst += (size_t)e * R * C;
  const int r0 = blockIdx.x * 64, c0 = blockIdx.y * 64;
  __shared__ unsigned short Ts[64][68];
  const int t = threadIdx.x;
  const int rr = t >> 4, cc = (t & 15) * 4;
#pragma unroll
  for (int p = 0; p < 4; ++p) {
    int r = rr + p * 16;
    float4 v = *(const float4*)(src + (size_t)(r0 + r) * C + c0 + cc);
    Ts[cc + 0][r] = f2bf(v.x);
    Ts[cc + 1][r] = f2bf(v.y);
    Ts[cc + 2][r] = f2bf(v.z);
    Ts[cc + 3][r] = f2bf(v.w);
  }
  __syncthreads();
  const int cr = t >> 3, rq = (t & 7) * 8;
#pragma unroll
  for (int p = 0; p < 2; ++p) {
    int c = cr + p * 32;
    ushort4 a = *(ushort4*)&Ts[c][rq];
    ushort4 b = *(ushort4*)&Ts[c][rq + 4];
    *(ushort4*)(dst + (size_t)(c0 + c) * R + r0 + rq) = a;
    *(ushort4*)(dst + (size_t)(c0 + c) * R + r0 + rq + 4) = b;
  }
}

// ---------------- grouped bf16 GEMM, 128x128 tile, BK=32, double-buffered prefetch ----------------
// LDS layout per tile: [4 k-units][128 rows][8 elems] (unit-major; DMA-linear, 2-way-max reads)
// PASS 1: Hmat = gelu(Xg * W1T^T + b1)
// PASS 2 (z=0,1 k-slices): out[tok] += score * (Hmat_slice * W2T_slice^T [+ b2 if z==0])
template <int PASS>
__global__ __launch_bounds__(256, 4) void moe_gemm3(
    const unsigned short* __restrict__ Asrc,
    const unsigned short* __restrict__ Bt,
    const float* __restrict__ bias,
    const int* __restrict__ offsets,
    const int* __restrict__ tiles,
    const int* __restrict__ ntiles,
    const int* __restrict__ pairmap,
    const float* __restrict__ score,
    unsigned short* __restrict__ Hmat,
    float* __restrict__ out) {
  constexpr int K  = (PASS == 1) ? DIM : HID;   // full reduction dim (A row stride)
  constexpr int NS = (PASS == 1) ? HID : DIM;   // output width
  constexpr int KS = (PASS == 1) ? 1 : 2;       // k-slices
  constexpr int KL = K / KS;                    // k per slice
  constexpr int NT = KL / 32;                   // K-iterations

  const int tt = blockIdx.x;
  if (tt >= ntiles[0]) return;
  const int pk = tiles[tt];
  const int e  = pk >> 16;
  const int rt = pk & 0xffff;
  const int gbase = offsets[e];
  const int nc = offsets[e + 1] - gbase;
  const int rowsvalid = min(128, nc - rt * 128);
  const int ct = blockIdx.y;
  const int kz = (PASS == 1) ? 0 : blockIdx.z;
  const int koff = kz * KL;

  __shared__ unsigned short As[2][4096];   // 8KB per buffer
  __shared__ unsigned short Bs[2][4096];

  const int tid  = threadIdx.x;
  const int lane = tid & 63;
  const int w    = tid >> 6;
  const int wr = (w >> 1) * 64;
  const int wc = (w & 1) * 64;
  const int fr = lane & 15;
  const int fq = lane >> 4;

  f32x4 acc[4][4];
#pragma unroll
  for (int m = 0; m < 4; ++m)
#pragma unroll
    for (int n = 0; n < 4; ++n) acc[m][n] = (f32x4){0.f, 0.f, 0.f, 0.f};

  const unsigned short* Ab = Asrc + (size_t)(gbase + rt * 128) * K + koff;
  const unsigned short* Bb = Bt + (size_t)e * NS * K + (size_t)ct * 128 * K + koff;

  // staging geometry: thread -> row sr, k-units su and su+2
  const int su = w >> 1;                    // 0..1
  const int sr = (w & 1) * 64 + lane;       // 0..127
  const int sdst = w * 512 + lane * 8;      // element offset in LDS buffer

  auto stage = [&](int b, int k0) {
    const unsigned short* ga = Ab + (size_t)sr * K + k0 + su * 8;
    const unsigned short* gb = Bb + (size_t)sr * K + k0 + su * 8;
    load_lds16(ga,      &As[b][sdst]);
    load_lds16(gb,      &Bs[b][sdst]);
    load_lds16(ga + 16, &As[b][sdst + 2048]);
    load_lds16(gb + 16, &Bs[b][sdst + 2048]);
  };

  stage(0, 0);
  __syncthreads();   // prologue: buffer 0 ready

  for (int t = 0; t < NT; ++t) {
    if (t + 1 < NT) stage((t + 1) & 1, (t + 1) * 32);   // prefetch next tile
    const unsigned short* Ac = As[t & 1];
    const unsigned short* Bc = Bs[t & 1];
    bf16x8 af[4], bf[4];
#pragma unroll
    for (int m = 0; m < 4; ++m)
      af[m] = *(const bf16x8*)&Ac[fq * 1024 + (wr + m * 16 + fr) * 8];
#pragma unroll
    for (int n = 0; n < 4; ++n)
      bf[n] = *(const bf16x8*)&Bc[fq * 1024 + (wc + n * 16 + fr) * 8];
#pragma unroll
    for (int m = 0; m < 4; ++m)
#pragma unroll
      for (int n = 0; n < 4; ++n)
        acc[m][n] = __builtin_amdgcn_mfma_f32_16x16x32_bf16(af[m], bf[n], acc[m][n], 0, 0, 0);
    __syncthreads();  // next-tile DMA done (overlapped compute); buf[t&1] free to overwrite
  }

  if (PASS == 1) {
#pragma unroll
    for (int n = 0; n < 4; ++n) {
      const int col = ct * 128 + wc + n * 16 + fr;
      const float b1v = bias[(size_t)e * NS + col];
#pragma unroll
      for (int m = 0; m < 4; ++m) {
#pragma unroll
        for (int r = 0; r < 4; ++r) {
          const int lrow = wr + m * 16 + fq * 4 + r;
          if (lrow < rowsvalid) {
            float v = acc[m][n][r] + b1v;
            v = 0.5f * v * (1.f + erff(v * 0.70710678118654752440f));
            Hmat[(size_t)(gbase + rt * 128 + lrow) * HID + col] = f2bf(v);
          }
        }
      }
    }
  } else {
    float b2v[4];
#pragma unroll
    for (int n = 0; n < 4; ++n)
      b2v[n] = (kz == 0) ? bias[(size_t)e * NS + ct * 128 + wc + n * 16 + fr] : 0.f;
#pragma unroll
    for (int m = 0; m < 4; ++m) {
#pragma unroll
      for (int r = 0; r < 4; ++r) {
        const int lrow = wr + m * 16 + fq * 4 + r;
        if (lrow < rowsvalid) {
          const int g = gbase + rt * 128 + lrow;
          const int ent = pairmap[g];
          const int tok = ent >> 1;
          const float s = score[ent];
#pragma unroll
          for (int n = 0; n < 4; ++n) {
            const int col = ct * 128 + wc + n * 16 + fr;
            atomicAdd(&out[(size_t)tok * DIM + col], s * (acc[m][n][r] + b2v[n]));
          }
        }
      }
    }
  }
}

// ============== fallback: round-1 GEMM (fp32 weights converted in-loop) ==============
template <int PASS>
__global__ __launch_bounds__(256) void moe_gemm(
    const unsigned short* __restrict__ Asrc,
    const float* __restrict__ Bsrc,
    const float* __restrict__ bias,
    const int* __restrict__ offsets,
    const int* __restrict__ pairmap,
    const float* __restrict__ score,
    unsigned short* __restrict__ Hmat,
    float* __restrict__ out) {
  constexpr int K  = (PASS == 1) ? DIM : HID;
  constexpr int NS = (PASS == 1) ? HID : DIM;
  const int e = blockIdx.z;
  const int gbase = offsets[e];
  const int nc = offsets[e + 1] - gbase;
  const int rt = blockIdx.x;
  if (rt * 128 >= nc) return;
  const int rowsvalid = min(128, nc - rt * 128);
  const int ct = blockIdx.y;
  __shared__ unsigned short As[128 * 40];
  __shared__ unsigned short Bs[128 * 40];
  const int tid  = threadIdx.x;
  const int lane = tid & 63;
  const int wid  = tid >> 6;
  const int wr = (wid >> 1) * 64;
  const int wc = (wid & 1) * 64;
  const int fr = lane & 15;
  const int fq = lane >> 4;
  f32x4 acc[4][4];
#pragma unroll
  for (int m = 0; m < 4; ++m)
#pragma unroll
    for (int n = 0; n < 4; ++n) acc[m][n] = (f32x4){0.f, 0.f, 0.f, 0.f};
  const int ar = tid >> 1;
  const int ak = (tid & 1) * 16;
  int arow = rt * 128 + ((ar < rowsvalid) ? ar : 0);
  const unsigned short* Aptr = Asrc + (size_t)(gbase + arow) * K + ak;
  const int bc = (tid & 31) * 4;
  const int bk = (tid >> 5) * 4;
  const float* Bptr = Bsrc + (size_t)e * K * NS + (size_t)bk * NS + ct * 128 + bc;
  for (int k0 = 0; k0 < K; k0 += 32) {
    uint4 av0 = *(const uint4*)(Aptr + k0);
    uint4 av1 = *(const uint4*)(Aptr + k0 + 8);
    const float* bp = Bptr + (size_t)k0 * NS;
    float4 w0 = *(const float4*)(bp);
    float4 w1 = *(const float4*)(bp + NS);
    float4 w2 = *(const float4*)(bp + 2 * NS);
    float4 w3 = *(const float4*)(bp + 3 * NS);
    __syncthreads();
    *(uint4*)&As[ar * 40 + ak]     = av0;
    *(uint4*)&As[ar * 40 + ak + 8] = av1;
    {
      uint2 pv;
      pv.x = (unsigned int)f2bf(w0.x) | ((unsigned int)f2bf(w1.x) << 16);
      pv.y = (unsigned int)f2bf(w2.x) | ((unsigned int)f2bf(w3.x) << 16);
      *(uint2*)&Bs[(bc + 0) * 40 + bk] = pv;
      pv.x = (unsigned int)f2bf(w0.y) | ((unsigned int)f2bf(w1.y) << 16);
      pv.y = (unsigned int)f2bf(w2.y) | ((unsigned int)f2bf(w3.y) << 16);
      *(uint2*)&Bs[(bc + 1) * 40 + bk] = pv;
      pv.x = (unsigned int)f2bf(w0.z) | ((unsigned int)f2bf(w1.z) << 16);
      pv.y = (unsigned int)f2bf(w2.z) | ((unsigned int)f2bf(w3.z) << 16);
      *(uint2*)&Bs[(bc + 2) * 40 + bk] = pv;
      pv.x = (unsigned int)f2bf(w0.w) | ((unsigned int)f2bf(w1.w) << 16);
      pv.y = (unsigned int)f2bf(w2.w) | ((unsigned int)f2bf(w3.w) << 16);
      *(uint2*)&Bs[(bc + 3) * 40 + bk] = pv;
    }
    __syncthreads();
    bf16x8 af[4], bfr[4];
#pragma unroll
    for (int m = 0; m < 4; ++m)
      af[m] = *(const bf16x8*)&As[(wr + m * 16 + fr) * 40 + fq * 8];
#pragma unroll
    for (int n = 0; n < 4; ++n)
      bfr[n] = *(const bf16x8*)&Bs[(wc + n * 16 + fr) * 40 + fq * 8];
#pragma unroll
    for (int m = 0; m < 4; ++m)
#pragma unroll
      for (int n = 0; n < 4; ++n)
        acc[m][n] = __builtin_amdgcn_mfma_f32_16x16x32_bf16(af[m], bfr[n], acc[m][n], 0, 0, 0);
  }
  if (PASS == 1) {
#pragma unroll
    for (int n = 0; n < 4; ++n) {
      int col = ct * 128 + wc + n * 16 + fr;
      float b1v = bias[(size_t)e * NS + col];
#pragma unroll
      for (int m = 0; m < 4; ++m) {
#pragma unroll
        for (int r = 0; r < 4; ++r) {
          int lrow = wr + m * 16 + fq * 4 + r;
          if (lrow < rowsvalid) {
            float v = acc[m][n][r] + b1v;
            v = 0.5f * v * (1.f + erff(v * 0.70710678118654752440f));
            Hmat[(size_t)(gbase + rt * 128 + lrow) * HID + col] = f2bf(v);
          }
        }
      }
    }
  } else {
    float b2v[4];
#pragma unroll
    for (int n = 0; n < 4; ++n)
      b2v[n] = bias[(size_t)e * NS + ct * 128 + wc + n * 16 + fr];
#pragma unroll
    for (int m = 0; m < 4; ++m) {
#pragma unroll
      for (int r = 0; r < 4; ++r) {
        int lrow = wr + m * 16 + fq * 4 + r;
        if (lrow < rowsvalid) {
          int g = gbase + rt * 128 + lrow;
          int ent = pairmap[g];
          int tok = ent >> 1;
          float s = score[ent];
#pragma unroll
          for (int n = 0; n < 4; ++n) {
            int col = ct * 128 + wc + n * 16 + fr;
            atomicAdd(&out[(size_t)tok * DIM + col], s * (acc[m][n][r] + b2v[n]));
          }
        }
      }
    }
  }
}

extern "C" void kernel_launch(void* const* d_in, const int* in_sizes, int n_in,
                              void* d_out, int out_size, void* d_ws, size_t ws_size,
                              hipStream_t stream) {
  const float* x  = (const float*)d_in[0];
  const float* W1 = (const float*)d_in[1];
  const float* b1 = (const float*)d_in[2];
  const float* W2 = (const float*)d_in[3];
  const float* b2 = (const float*)d_in[4];
  const float* Wg = (const float*)d_in[5];
  const float* bg = (const float*)d_in[6];
  float* out = (float*)d_out;
  const int N  = in_sizes[0] / DIM;   // tokens (4096)
  const int NP = N * TOPK;            // pairs (8192)
  const int MAXT = NP / 128 + NEXP;   // worst-case row tiles (72)

  char* ws = (char*)d_ws;
  size_t off = 0;
  auto alloc = [&](size_t bytes) -> void* {
    void* p = ws + off;
    off = (off + bytes + 255) & ~(size_t)255;
    return p;
  };
  int*   count      = (int*)alloc(NEXP * sizeof(int));
  int*   offsets    = (int*)alloc((NEXP + 1) * sizeof(int));
  int*   tiles      = (int*)alloc((size_t)MAXT * sizeof(int));
  int*   ntiles     = (int*)alloc(sizeof(int));
  float* topk_score = (float*)alloc((size_t)NP * sizeof(float));
  int*   lists      = (int*)alloc((size_t)NEXP * N * sizeof(int));
  int*   pairmap    = (int*)alloc((size_t)NP * sizeof(int));
  // padded by 128 rows: GEMM A-staging reads past the last valid row of a tile
  unsigned short* Xg   = (unsigned short*)alloc((size_t)(NP + 128) * DIM * sizeof(unsigned short));
  unsigned short* Hmat = (unsigned short*)alloc((size_t)(NP + 128) * HID * sizeof(unsigned short));
  unsigned short* W1T = (unsigned short*)alloc((size_t)NEXP * DIM * HID * sizeof(unsigned short));
  unsigned short* W2T = (unsigned short*)alloc((size_t)NEXP * HID * DIM * sizeof(unsigned short));
  size_t need_full = off;

  hipMemsetAsync(count, 0, NEXP * sizeof(int), stream);
  gate_kernel<<<N, 64, 0, stream>>>(x, Wg, bg, topk_score, count, lists, N);
  offsets_kernel<<<1, 64, 0, stream>>>(count, offsets, tiles, ntiles);
  gather_kernel<<<NP, DIM / 4, 0, stream>>>(x, offsets, lists, Xg, pairmap, N);
  hipMemsetAsync(out, 0, (size_t)out_size * sizeof(float), stream);

  if (ws_size >= need_full) {
    // one-time weight transpose-convert to bf16 K-contiguous
    dim3 tg1(DIM / 64, HID / 64, NEXP);
    transpose_convert<<<tg1, 256, 0, stream>>>(W1, W1T, DIM, HID);
    dim3 tg2(HID / 64, DIM / 64, NEXP);
    transpose_convert<<<tg2, 256, 0, stream>>>(W2, W2T, HID, DIM);

    dim3 g1(MAXT, HID / 128, 1);
    moe_gemm3<1><<<g1, 256, 0, stream>>>(Xg, W1T, b1, offsets, tiles, ntiles,
                                         pairmap, topk_score, Hmat, out);
    dim3 g2(MAXT, DIM / 128, 2);
    moe_gemm3<2><<<g2, 256, 0, stream>>>(Hmat, W2T, b2, offsets, tiles, ntiles,
                                         pairmap, topk_score, Hmat, out);
  } else {
    const int RT = (N + 127) / 128;
    dim3 g1(RT, HID / 128, NEXP);
    moe_gemm<1><<<g1, 256, 0, stream>>>(Xg, W1, b1, offsets, pairmap, topk_score, Hmat, out);
    dim3 g2(RT, DIM / 128, NEXP);
    moe_gemm<2><<<g2, 256, 0, stream>>>(Hmat, W2, b2, offsets, pairmap, topk_score, Hmat, out);
  }
}